// Round 1
// baseline (2839.172 us; speedup 1.0000x reference)
//
#include <hip/hip_runtime.h>

#define N_NODES 100000
#define N_EDGES 1600000
#define D 128

// ---------------------------------------------------------------------------
// Zero-fill T accumulator (d_ws is re-poisoned to 0xAA before every call).
// ---------------------------------------------------------------------------
__global__ void zero_kernel(float4* __restrict__ p, long long n4) {
    long long i = (long long)blockIdx.x * blockDim.x + threadIdx.x;
    if (i < n4) p[i] = make_float4(0.f, 0.f, 0.f, 0.f);
}

// ---------------------------------------------------------------------------
// Scatter: T[dst] += val * x[src].  32 threads per edge, float4 per thread.
// ---------------------------------------------------------------------------
__global__ __launch_bounds__(256) void scatter_kernel(
        const float* __restrict__ x,
        const int*   __restrict__ src,
        const int*   __restrict__ dst,
        const float* __restrict__ val,
        float*       __restrict__ T) {
    long long tid = (long long)blockIdx.x * blockDim.x + threadIdx.x;
    int e = (int)(tid >> 5);
    if (e >= N_EDGES) return;
    int f = ((int)tid & 31) << 2;           // feature offset 0,4,...,124

    int   s = src[e];
    int   d = dst[e];
    float v = val[e];

    const float4 xv = *(const float4*)(x + (long long)s * D + f);
    float* tp = T + (long long)d * D + f;
    atomicAdd(tp + 0, xv.x * v);
    atomicAdd(tp + 1, xv.y * v);
    atomicAdd(tp + 2, xv.z * v);
    atomicAdd(tp + 3, xv.w * v);
}

// ---------------------------------------------------------------------------
// Dense projection: Z = T @ W.  Block computes 32 rows x 128 cols.
// T tile staged in LDS (16 KB); W stays hot in L1/L2 (64 KB total).
// ---------------------------------------------------------------------------
#define ROWS 32
__global__ __launch_bounds__(256) void gemm_kernel(
        const float* __restrict__ T,
        const float* __restrict__ W,
        float*       __restrict__ Z) {
    __shared__ float lt[ROWS][D];

    const int block_row = blockIdx.x * ROWS;
    const int tid = threadIdx.x;

    // Stage T tile: 32*128 floats = 1024 float4s, 4 per thread, coalesced.
    const float4* tsrc = (const float4*)(T + (long long)block_row * D);
    float4* ldst = (float4*)(&lt[0][0]);
#pragma unroll
    for (int i = 0; i < (ROWS * D / 4) / 256; ++i)
        ldst[tid + i * 256] = tsrc[tid + i * 256];
    __syncthreads();

    const int col = tid & (D - 1);          // 0..127
    const int rg  = tid >> 7;               // 0..1

    float acc[16];
#pragma unroll
    for (int r = 0; r < 16; ++r) acc[r] = 0.f;

    for (int k = 0; k < D; ++k) {
        float w = W[k * D + col];           // coalesced, L2-hot
#pragma unroll
        for (int r = 0; r < 16; ++r)
            acc[r] += lt[rg + 2 * r][k] * w;  // LDS broadcast (wave-uniform addr)
    }

#pragma unroll
    for (int r = 0; r < 16; ++r)
        Z[(long long)(block_row + rg + 2 * r) * D + col] = acc[r];
}

// ---------------------------------------------------------------------------
extern "C" void kernel_launch(void* const* d_in, const int* in_sizes, int n_in,
                              void* d_out, int out_size, void* d_ws, size_t ws_size,
                              hipStream_t stream) {
    const float* x    = (const float*)d_in[0];   // [N_NODES, D]
    const float* W    = (const float*)d_in[1];   // [D, D]
    const int*   esrc = (const int*)  d_in[2];   // [N_EDGES]
    const int*   edst = (const int*)  d_in[3];   // [N_EDGES]
    const float* eval_= (const float*)d_in[4];   // [N_EDGES]
    float*       Z    = (float*)d_out;           // [N_NODES, D]
    float*       T    = (float*)d_ws;            // [N_NODES, D] accumulator (51.2 MB)

    // 1) T = 0
    long long n4 = (long long)N_NODES * D / 4;
    zero_kernel<<<(int)((n4 + 255) / 256), 256, 0, stream>>>((float4*)T, n4);

    // 2) T[dst] += val * x[src]
    long long nthreads = (long long)N_EDGES * 32;
    scatter_kernel<<<(int)((nthreads + 255) / 256), 256, 0, stream>>>(x, esrc, edst, eval_, T);

    // 3) Z = T @ W
    gemm_kernel<<<N_NODES / ROWS, 256, 0, stream>>>(T, W, Z);
}

// Round 2
// 435.484 us; speedup vs baseline: 6.5196x; 6.5196x over previous
//
#include <hip/hip_runtime.h>

#define N_NODES 100000
#define N_EDGES 1600000
#define D 128
#define CHUNK 1024
#define NCHUNK ((N_NODES + CHUNK - 1) / CHUNK)   // 98

// ---------------------------------------------------------------------------
// Counting-sort pipeline: hist -> scan(3 kernels) -> reorder
// ---------------------------------------------------------------------------
__global__ void zero_cnt_kernel(int* __restrict__ cnt) {
    int i = blockIdx.x * blockDim.x + threadIdx.x;
    if (i < N_NODES) cnt[i] = 0;
}

__global__ void hist_kernel(const int* __restrict__ dst, int* __restrict__ cnt) {
    int e = blockIdx.x * blockDim.x + threadIdx.x;
    if (e < N_EDGES) atomicAdd(&cnt[dst[e]], 1);
}

// per-chunk (1024 elements) sums
__global__ __launch_bounds__(256) void scan1_kernel(const int* __restrict__ cnt,
                                                    int* __restrict__ partial) {
    __shared__ int ls[4];
    int b = blockIdx.x, t = threadIdx.x;
    int base = b * CHUNK + t * 4;
    int s = 0;
#pragma unroll
    for (int j = 0; j < 4; ++j) {
        int i = base + j;
        if (i < N_NODES) s += cnt[i];
    }
    for (int o = 32; o > 0; o >>= 1) s += __shfl_down(s, o, 64);
    if ((t & 63) == 0) ls[t >> 6] = s;
    __syncthreads();
    if (t == 0) partial[b] = ls[0] + ls[1] + ls[2] + ls[3];
}

// exclusive scan of the chunk partials (single block)
__global__ __launch_bounds__(128) void scan2_kernel(const int* __restrict__ partial,
                                                    int* __restrict__ chunk_base) {
    __shared__ int sc[128];
    int t = threadIdx.x;
    int v = (t < NCHUNK) ? partial[t] : 0;
    sc[t] = v;
    __syncthreads();
    for (int o = 1; o < 128; o <<= 1) {
        int u = (t >= o) ? sc[t - o] : 0;
        __syncthreads();
        sc[t] += u;
        __syncthreads();
    }
    if (t < NCHUNK) chunk_base[t] = sc[t] - v;  // exclusive
}

// full exclusive positions: cur[i] (cursor copy) and off[i+1] (inclusive)
__global__ __launch_bounds__(256) void scan3_kernel(const int* __restrict__ cnt,
                                                    const int* __restrict__ chunk_base,
                                                    int* __restrict__ off,
                                                    int* __restrict__ cur) {
    __shared__ int sc[256];
    int b = blockIdx.x, t = threadIdx.x;
    int base = b * CHUNK + t * 4;
    int c[4];
    int s = 0;
#pragma unroll
    for (int j = 0; j < 4; ++j) {
        int i = base + j;
        c[j] = (i < N_NODES) ? cnt[i] : 0;
        s += c[j];
    }
    sc[t] = s;
    __syncthreads();
    for (int o = 1; o < 256; o <<= 1) {
        int u = (t >= o) ? sc[t - o] : 0;
        __syncthreads();
        sc[t] += u;
        __syncthreads();
    }
    int run = chunk_base[b] + sc[t] - s;  // exclusive base of this thread's 4
#pragma unroll
    for (int j = 0; j < 4; ++j) {
        int i = base + j;
        if (i < N_NODES) {
            cur[i] = run;
            off[i + 1] = run + c[j];
            run += c[j];
        }
    }
    if (b == 0 && t == 0) off[0] = 0;
}

__global__ void reorder_kernel(const int* __restrict__ src, const int* __restrict__ dst,
                               const float* __restrict__ val, int* __restrict__ cur,
                               int2* __restrict__ epack) {
    int e = blockIdx.x * blockDim.x + threadIdx.x;
    if (e < N_EDGES) {
        int d = dst[e];
        int pos = atomicAdd(&cur[d], 1);
        epack[pos] = make_int2(src[e], __float_as_int(val[e]));
    }
}

// ---------------------------------------------------------------------------
// Fused gather (segment-sum into LDS) + projection GEMM.
// Block = 256 threads, 32 dst rows. Gather: 32 lanes per row (float4/lane),
// 8 rows per pass x 4 passes. GEMM: 4x4 register tile per thread.
// ---------------------------------------------------------------------------
#define ROWS 32
__global__ __launch_bounds__(256) void gather_gemm_kernel(
        const float* __restrict__ x, const float* __restrict__ W,
        const int* __restrict__ off, const int2* __restrict__ epack,
        float* __restrict__ Z) {
    __shared__ float lt[ROWS][D];   // 16 KB
    const int tid = threadIdx.x;
    const int block_row = blockIdx.x * ROWS;
    const int g = tid >> 5;         // row group 0..7
    const int l = tid & 31;         // float4 slot within 512B row
    const float4* x4 = (const float4*)x;

#pragma unroll
    for (int pass = 0; pass < 4; ++pass) {
        int r = pass * 8 + g;
        int node = block_row + r;
        int e0 = off[node], e1 = off[node + 1];
        float4 acc = make_float4(0.f, 0.f, 0.f, 0.f);
        int e = e0;
        for (; e + 2 <= e1; e += 2) {          // 2-way unroll: 2 x-loads in flight
            int2 p0 = epack[e];
            int2 p1 = epack[e + 1];
            float4 a = x4[(long long)p0.x * (D / 4) + l];
            float4 b = x4[(long long)p1.x * (D / 4) + l];
            float v0 = __int_as_float(p0.y), v1 = __int_as_float(p1.y);
            acc.x += v0 * a.x + v1 * b.x;
            acc.y += v0 * a.y + v1 * b.y;
            acc.z += v0 * a.z + v1 * b.z;
            acc.w += v0 * a.w + v1 * b.w;
        }
        if (e < e1) {
            int2 p0 = epack[e];
            float4 a = x4[(long long)p0.x * (D / 4) + l];
            float v0 = __int_as_float(p0.y);
            acc.x += v0 * a.x; acc.y += v0 * a.y;
            acc.z += v0 * a.z; acc.w += v0 * a.w;
        }
        ((float4*)lt[r])[l] = acc;
    }
    __syncthreads();

    // Phase 2: Z[block_row..+32) = lt @ W
    const int colb = tid & 31;             // cols colb + {0,32,64,96}
    const int row_base = (tid >> 5) * 4;   // rows row_base + {0..3}
    float acc[4][4];
#pragma unroll
    for (int r = 0; r < 4; ++r)
#pragma unroll
        for (int c = 0; c < 4; ++c) acc[r][c] = 0.f;

#pragma unroll 4
    for (int k = 0; k < D; ++k) {
        float w0 = W[k * D + colb];
        float w1 = W[k * D + colb + 32];
        float w2 = W[k * D + colb + 64];
        float w3 = W[k * D + colb + 96];
        float t0 = lt[row_base + 0][k];
        float t1 = lt[row_base + 1][k];
        float t2 = lt[row_base + 2][k];
        float t3 = lt[row_base + 3][k];
        acc[0][0] += t0 * w0; acc[0][1] += t0 * w1; acc[0][2] += t0 * w2; acc[0][3] += t0 * w3;
        acc[1][0] += t1 * w0; acc[1][1] += t1 * w1; acc[1][2] += t1 * w2; acc[1][3] += t1 * w3;
        acc[2][0] += t2 * w0; acc[2][1] += t2 * w1; acc[2][2] += t2 * w2; acc[2][3] += t2 * w3;
        acc[3][0] += t3 * w0; acc[3][1] += t3 * w1; acc[3][2] += t3 * w2; acc[3][3] += t3 * w3;
    }

#pragma unroll
    for (int r = 0; r < 4; ++r)
#pragma unroll
        for (int c = 0; c < 4; ++c)
            Z[(long long)(block_row + row_base + r) * D + colb + 32 * c] = acc[r][c];
}

// ---------------------------------------------------------------------------
extern "C" void kernel_launch(void* const* d_in, const int* in_sizes, int n_in,
                              void* d_out, int out_size, void* d_ws, size_t ws_size,
                              hipStream_t stream) {
    const float* x    = (const float*)d_in[0];   // [N_NODES, D]
    const float* W    = (const float*)d_in[1];   // [D, D]
    const int*   esrc = (const int*)  d_in[2];   // [N_EDGES]
    const int*   edst = (const int*)  d_in[3];   // [N_EDGES]
    const float* eval_= (const float*)d_in[4];   // [N_EDGES]
    float*       Z    = (float*)d_out;           // [N_NODES, D]

    // Workspace layout (all re-derived every call; ws is re-poisoned)
    char* w = (char*)d_ws;
    int*  off        = (int*) (w + 0);          // [N_NODES+1]
    int*  cur        = (int*) (w + 400016);     // [N_NODES]
    int*  cnt        = (int*) (w + 800016);     // [N_NODES]
    int*  partial    = (int*) (w + 1200016);    // [NCHUNK]
    int*  chunk_base = (int*) (w + 1200416);    // [NCHUNK]
    int2* epack      = (int2*)(w + 1200816);    // [N_EDGES] (src, val-bits)

    zero_cnt_kernel<<<(N_NODES + 255) / 256, 256, 0, stream>>>(cnt);
    hist_kernel<<<(N_EDGES + 255) / 256, 256, 0, stream>>>(edst, cnt);
    scan1_kernel<<<NCHUNK, 256, 0, stream>>>(cnt, partial);
    scan2_kernel<<<1, 128, 0, stream>>>(partial, chunk_base);
    scan3_kernel<<<NCHUNK, 256, 0, stream>>>(cnt, chunk_base, off, cur);
    reorder_kernel<<<(N_EDGES + 255) / 256, 256, 0, stream>>>(esrc, edst, eval_, cur, epack);
    gather_gemm_kernel<<<N_NODES / ROWS, 256, 0, stream>>>(x, W, off, epack, Z);
}

// Round 3
// 355.787 us; speedup vs baseline: 7.9800x; 1.2240x over previous
//
#include <hip/hip_runtime.h>

#define N_NODES 100000
#define N_EDGES 1600000
#define D 128
#define CHUNK 1024
#define NCHUNK ((N_NODES + CHUNK - 1) / CHUNK)   // 98

// ---------------------------------------------------------------------------
__global__ void zero_cnt_kernel(int* __restrict__ cnt) {
    int i = blockIdx.x * blockDim.x + threadIdx.x;
    if (i < N_NODES) cnt[i] = 0;
}

// hist + per-edge rank in one pass (atomic returns old count)
__global__ void hist_rank_kernel(const int* __restrict__ dst, int* __restrict__ cnt,
                                 int* __restrict__ rank) {
    int e = blockIdx.x * blockDim.x + threadIdx.x;
    if (e < N_EDGES) rank[e] = atomicAdd(&cnt[dst[e]], 1);
}

// per-chunk (1024 elements) sums
__global__ __launch_bounds__(256) void scan1_kernel(const int* __restrict__ cnt,
                                                    int* __restrict__ partial) {
    __shared__ int ls[4];
    int b = blockIdx.x, t = threadIdx.x;
    int base = b * CHUNK + t * 4;
    int s = 0;
#pragma unroll
    for (int j = 0; j < 4; ++j) {
        int i = base + j;
        if (i < N_NODES) s += cnt[i];
    }
    for (int o = 32; o > 0; o >>= 1) s += __shfl_down(s, o, 64);
    if ((t & 63) == 0) ls[t >> 6] = s;
    __syncthreads();
    if (t == 0) partial[b] = ls[0] + ls[1] + ls[2] + ls[3];
}

// exclusive scan of chunk partials (single block)
__global__ __launch_bounds__(128) void scan2_kernel(const int* __restrict__ partial,
                                                    int* __restrict__ chunk_base) {
    __shared__ int sc[128];
    int t = threadIdx.x;
    int v = (t < NCHUNK) ? partial[t] : 0;
    sc[t] = v;
    __syncthreads();
    for (int o = 1; o < 128; o <<= 1) {
        int u = (t >= o) ? sc[t - o] : 0;
        __syncthreads();
        sc[t] += u;
        __syncthreads();
    }
    if (t < NCHUNK) chunk_base[t] = sc[t] - v;  // exclusive
}

// full exclusive offsets
__global__ __launch_bounds__(256) void scan3_kernel(const int* __restrict__ cnt,
                                                    const int* __restrict__ chunk_base,
                                                    int* __restrict__ off) {
    __shared__ int sc[256];
    int b = blockIdx.x, t = threadIdx.x;
    int base = b * CHUNK + t * 4;
    int c[4];
    int s = 0;
#pragma unroll
    for (int j = 0; j < 4; ++j) {
        int i = base + j;
        c[j] = (i < N_NODES) ? cnt[i] : 0;
        s += c[j];
    }
    sc[t] = s;
    __syncthreads();
    for (int o = 1; o < 256; o <<= 1) {
        int u = (t >= o) ? sc[t - o] : 0;
        __syncthreads();
        sc[t] += u;
        __syncthreads();
    }
    int run = chunk_base[b] + sc[t] - s;
#pragma unroll
    for (int j = 0; j < 4; ++j) {
        int i = base + j;
        if (i < N_NODES) {
            off[i + 1] = run + c[j];
            run += c[j];
        }
    }
    if (b == 0 && t == 0) off[0] = 0;
}

// atomic-free reorder: pos = off[dst] + rank
__global__ void scatter_pos_kernel(const int* __restrict__ src, const int* __restrict__ dst,
                                   const float* __restrict__ val, const int* __restrict__ rank,
                                   const int* __restrict__ off, int2* __restrict__ epack) {
    int e = blockIdx.x * blockDim.x + threadIdx.x;
    if (e < N_EDGES) {
        int pos = off[dst[e]] + rank[e];
        epack[pos] = make_int2(src[e], __float_as_int(val[e]));
    }
}

// ---------------------------------------------------------------------------
// Y = X @ W, stored as packed bf16 pairs (uint). Block = 256 thr, 32 rows.
// ---------------------------------------------------------------------------
__device__ __forceinline__ unsigned bfpack(float a, float b) {
    unsigned ua = __float_as_uint(a), ub = __float_as_uint(b);
    ua = (ua + 0x7fffu + ((ua >> 16) & 1u)) >> 16;           // RNE, low half
    ub = (ub + 0x7fffu + ((ub >> 16) & 1u)) & 0xffff0000u;   // RNE, high half
    return ub | ua;
}

__global__ __launch_bounds__(256) void gemm_xw_kernel(
        const float* __restrict__ X, const float* __restrict__ W,
        unsigned* __restrict__ Yu) {
    __shared__ float lt[32][D];   // 16 KB
    const int tid = threadIdx.x;
    const int block_row = blockIdx.x * 32;

    // stage X tile (coalesced float4)
    const float4* xs = (const float4*)(X + (long long)block_row * D);
    float4* ld = (float4*)(&lt[0][0]);
#pragma unroll
    for (int i = 0; i < 4; ++i) ld[tid + i * 256] = xs[tid + i * 256];
    __syncthreads();

    const int c2 = tid & 63;     // column pair: cols {2*c2, 2*c2+1}
    const int rg = tid >> 6;     // 0..3 (uniform per wave)
    const float2* W2 = (const float2*)W;

    float acc[8][2];
#pragma unroll
    for (int j = 0; j < 8; ++j) { acc[j][0] = 0.f; acc[j][1] = 0.f; }

#pragma unroll 2
    for (int k = 0; k < D; ++k) {
        float2 w = W2[k * 64 + c2];
#pragma unroll
        for (int j = 0; j < 8; ++j) {
            float t = lt[j * 4 + rg][k];   // LDS broadcast within wave
            acc[j][0] += t * w.x;
            acc[j][1] += t * w.y;
        }
    }

#pragma unroll
    for (int j = 0; j < 8; ++j)
        Yu[(long long)(block_row + j * 4 + rg) * 64 + c2] = bfpack(acc[j][0], acc[j][1]);
}

// ---------------------------------------------------------------------------
// Gather: Z[n] = sum_e val_e * Y[src_e].  One 64-lane wave per dst row,
// each lane handles a bf16 pair (4 B), f32 accumulate, direct f32 store.
// ---------------------------------------------------------------------------
__global__ __launch_bounds__(256) void gather_kernel(
        const unsigned* __restrict__ Yu, const int* __restrict__ off,
        const int2* __restrict__ epack, float* __restrict__ Z) {
    const int n = blockIdx.x * 4 + (threadIdx.x >> 6);
    if (n >= N_NODES) return;
    const int lane = threadIdx.x & 63;

    int e0 = off[n], e1 = off[n + 1];
    float ax = 0.f, ay = 0.f;

    int e = e0;
    for (; e + 4 <= e1; e += 4) {
        int2 p0 = epack[e + 0];
        int2 p1 = epack[e + 1];
        int2 p2 = epack[e + 2];
        int2 p3 = epack[e + 3];
        unsigned y0 = Yu[(long long)p0.x * 64 + lane];
        unsigned y1 = Yu[(long long)p1.x * 64 + lane];
        unsigned y2 = Yu[(long long)p2.x * 64 + lane];
        unsigned y3 = Yu[(long long)p3.x * 64 + lane];
        float v0 = __int_as_float(p0.y), v1 = __int_as_float(p1.y);
        float v2 = __int_as_float(p2.y), v3 = __int_as_float(p3.y);
        ax += v0 * __uint_as_float(y0 << 16) + v1 * __uint_as_float(y1 << 16)
            + v2 * __uint_as_float(y2 << 16) + v3 * __uint_as_float(y3 << 16);
        ay += v0 * __uint_as_float(y0 & 0xffff0000u) + v1 * __uint_as_float(y1 & 0xffff0000u)
            + v2 * __uint_as_float(y2 & 0xffff0000u) + v3 * __uint_as_float(y3 & 0xffff0000u);
    }
    for (; e < e1; ++e) {
        int2 p = epack[e];
        unsigned y = Yu[(long long)p.x * 64 + lane];
        float v = __int_as_float(p.y);
        ax += v * __uint_as_float(y << 16);
        ay += v * __uint_as_float(y & 0xffff0000u);
    }

    ((float2*)Z)[(long long)n * 64 + lane] = make_float2(ax, ay);
}

// ---------------------------------------------------------------------------
extern "C" void kernel_launch(void* const* d_in, const int* in_sizes, int n_in,
                              void* d_out, int out_size, void* d_ws, size_t ws_size,
                              hipStream_t stream) {
    const float* x    = (const float*)d_in[0];   // [N_NODES, D]
    const float* W    = (const float*)d_in[1];   // [D, D]
    const int*   esrc = (const int*)  d_in[2];   // [N_EDGES]
    const int*   edst = (const int*)  d_in[3];   // [N_EDGES]
    const float* eval_= (const float*)d_in[4];   // [N_EDGES]
    float*       Z    = (float*)d_out;           // [N_NODES, D]

    // Workspace layout (bytes)
    char* w = (char*)d_ws;
    int*      off        = (int*)     (w + 0);         // [N_NODES+1]   -> 400016
    int*      cnt        = (int*)     (w + 400016);    // [N_NODES]     -> 800016
    int*      partial    = (int*)     (w + 800016);    // [NCHUNK]      -> 800416
    int*      chunk_base = (int*)     (w + 800416);    // [NCHUNK]      -> 800816
    int*      rank       = (int*)     (w + 800832);    // [N_EDGES]     -> 7200832
    int2*     epack      = (int2*)    (w + 7200832);   // [N_EDGES]     -> 20000832
    unsigned* Yu         = (unsigned*)(w + 20000832);  // [N_NODES*64]  -> 45600832

    zero_cnt_kernel<<<(N_NODES + 255) / 256, 256, 0, stream>>>(cnt);
    hist_rank_kernel<<<(N_EDGES + 255) / 256, 256, 0, stream>>>(edst, cnt, rank);
    scan1_kernel<<<NCHUNK, 256, 0, stream>>>(cnt, partial);
    scan2_kernel<<<1, 128, 0, stream>>>(partial, chunk_base);
    scan3_kernel<<<NCHUNK, 256, 0, stream>>>(cnt, chunk_base, off);
    scatter_pos_kernel<<<(N_EDGES + 255) / 256, 256, 0, stream>>>(esrc, edst, eval_, rank, off, epack);
    gemm_xw_kernel<<<N_NODES / 32, 256, 0, stream>>>(x, W, Yu);
    gather_kernel<<<(N_NODES + 3) / 4, 256, 0, stream>>>(Yu, off, epack, Z);
}

// Round 4
// 301.482 us; speedup vs baseline: 9.4174x; 1.1801x over previous
//
#include <hip/hip_runtime.h>

#define N_NODES 100000
#define N_EDGES 1600000
#define D 128
#define CHUNK 1024
#define NCHUNK ((N_NODES + CHUNK - 1) / CHUNK)   // 98

typedef __attribute__((ext_vector_type(8))) short bf16x8;
typedef __attribute__((ext_vector_type(4))) float f32x4;
typedef unsigned short ushort_t;

__device__ __forceinline__ ushort_t bf(float f) {   // f32 -> bf16 RNE
    unsigned u = __float_as_uint(f);
    return (ushort_t)((u + 0x7fffu + ((u >> 16) & 1u)) >> 16);
}

// ---------------------------------------------------------------------------
__global__ void zero_cnt_kernel(int* __restrict__ cnt) {
    int i = blockIdx.x * blockDim.x + threadIdx.x;
    if (i < N_NODES) cnt[i] = 0;
}

// hist + per-edge rank in one pass (atomic returns old count); rank fits u16
__global__ void hist_rank_kernel(const int* __restrict__ dst, int* __restrict__ cnt,
                                 ushort_t* __restrict__ rank) {
    int e = blockIdx.x * blockDim.x + threadIdx.x;
    if (e < N_EDGES) rank[e] = (ushort_t)atomicAdd(&cnt[dst[e]], 1);
}

__global__ __launch_bounds__(256) void scan1_kernel(const int* __restrict__ cnt,
                                                    int* __restrict__ partial) {
    __shared__ int ls[4];
    int b = blockIdx.x, t = threadIdx.x;
    int base = b * CHUNK + t * 4;
    int s = 0;
#pragma unroll
    for (int j = 0; j < 4; ++j) {
        int i = base + j;
        if (i < N_NODES) s += cnt[i];
    }
    for (int o = 32; o > 0; o >>= 1) s += __shfl_down(s, o, 64);
    if ((t & 63) == 0) ls[t >> 6] = s;
    __syncthreads();
    if (t == 0) partial[b] = ls[0] + ls[1] + ls[2] + ls[3];
}

__global__ __launch_bounds__(128) void scan2_kernel(const int* __restrict__ partial,
                                                    int* __restrict__ chunk_base) {
    __shared__ int sc[128];
    int t = threadIdx.x;
    int v = (t < NCHUNK) ? partial[t] : 0;
    sc[t] = v;
    __syncthreads();
    for (int o = 1; o < 128; o <<= 1) {
        int u = (t >= o) ? sc[t - o] : 0;
        __syncthreads();
        sc[t] += u;
        __syncthreads();
    }
    if (t < NCHUNK) chunk_base[t] = sc[t] - v;  // exclusive
}

__global__ __launch_bounds__(256) void scan3_kernel(const int* __restrict__ cnt,
                                                    const int* __restrict__ chunk_base,
                                                    int* __restrict__ off) {
    __shared__ int sc[256];
    int b = blockIdx.x, t = threadIdx.x;
    int base = b * CHUNK + t * 4;
    int c[4];
    int s = 0;
#pragma unroll
    for (int j = 0; j < 4; ++j) {
        int i = base + j;
        c[j] = (i < N_NODES) ? cnt[i] : 0;
        s += c[j];
    }
    sc[t] = s;
    __syncthreads();
    for (int o = 1; o < 256; o <<= 1) {
        int u = (t >= o) ? sc[t - o] : 0;
        __syncthreads();
        sc[t] += u;
        __syncthreads();
    }
    int run = chunk_base[b] + sc[t] - s;
#pragma unroll
    for (int j = 0; j < 4; ++j) {
        int i = base + j;
        if (i < N_NODES) {
            off[i + 1] = run + c[j];
            run += c[j];
        }
    }
    if (b == 0 && t == 0) off[0] = 0;
}

// atomic-free reorder: pos = off[dst] + rank.
// epack = src (17 bits) | val_q15 << 17  (val in [0,1), 15-bit fixed point)
__global__ void scatter_pos_kernel(const int* __restrict__ src, const int* __restrict__ dst,
                                   const float* __restrict__ val, const ushort_t* __restrict__ rank,
                                   const int* __restrict__ off, unsigned* __restrict__ epack) {
    int e = blockIdx.x * blockDim.x + threadIdx.x;
    if (e < N_EDGES) {
        int pos = off[dst[e]] + (int)rank[e];
        unsigned q = (unsigned)(val[e] * 32767.0f + 0.5f);  // 0..32767
        epack[pos] = ((unsigned)src[e]) | (q << 17);
    }
}

// ---------------------------------------------------------------------------
// W^T in bf16 (one-time tiny kernel; result is L2-hot for gemm blocks)
// ---------------------------------------------------------------------------
__global__ void wt_conv_kernel(const float* __restrict__ W, ushort_t* __restrict__ Wt) {
    int i = blockIdx.x * 256 + threadIdx.x;   // i < 128*128
    int n = i >> 7, k = i & 127;
    Wt[i] = bf(W[k * D + n]);
}

// ---------------------------------------------------------------------------
// Y = X @ W via bf16 MFMA. Block = 256 thr (4 waves), 64 rows/block.
// lx/lw rows padded +8 ushorts so fragment b128 reads are 2-way bank (free).
// ---------------------------------------------------------------------------
#define LP (D + 8)
__global__ __launch_bounds__(256) void gemm_xw_mfma(
        const float* __restrict__ X, const ushort_t* __restrict__ Wt,
        ushort_t* __restrict__ Y) {
    __shared__ ushort_t lx[64][LP];    // ~17.4 KB
    __shared__ ushort_t lw[D][LP];     // ~34.8 KB
    const int tid = threadIdx.x;
    const long long row0 = (long long)blockIdx.x * 64;

    // stage W^T: 128 rows x 16 chunks of 8 ushorts (16B)
#pragma unroll
    for (int it = 0; it < 8; ++it) {
        int c = tid + it * 256;            // 0..2047
        int r = c >> 4, c16 = c & 15;
        *(ulonglong2*)&lw[r][c16 * 8] = *(const ulonglong2*)(Wt + r * D + c16 * 8);
    }
    // stage X tile as bf16: 64 rows x 32 float4 chunks
#pragma unroll
    for (int it = 0; it < 8; ++it) {
        int c = tid + it * 256;            // 0..2047
        int r = c >> 5, c4 = c & 31;
        long long gr = row0 + r;
        if (gr >= N_NODES) gr = 0;         // clamp (stores guarded later)
        float4 v = *(const float4*)(X + gr * D + c4 * 4);
        ushort4 b4 = make_ushort4(bf(v.x), bf(v.y), bf(v.z), bf(v.w));
        *(ushort4*)&lx[r][c4 * 4] = b4;
    }
    __syncthreads();

    const int wave = tid >> 6, lane = tid & 63;
    const int mrow = lane & 15, quad = lane >> 4;

    f32x4 acc[8];
#pragma unroll
    for (int nt = 0; nt < 8; ++nt) acc[nt] = (f32x4){0.f, 0.f, 0.f, 0.f};

#pragma unroll
    for (int kc = 0; kc < 4; ++kc) {
        bf16x8 a = *(const bf16x8*)&lx[wave * 16 + mrow][kc * 32 + quad * 8];
#pragma unroll
        for (int nt = 0; nt < 8; ++nt) {
            bf16x8 b = *(const bf16x8*)&lw[nt * 16 + mrow][kc * 32 + quad * 8];
            acc[nt] = __builtin_amdgcn_mfma_f32_16x16x32_bf16(a, b, acc[nt], 0, 0, 0);
        }
    }

    const long long baserow = row0 + wave * 16 + quad * 4;
#pragma unroll
    for (int nt = 0; nt < 8; ++nt)
#pragma unroll
        for (int r = 0; r < 4; ++r) {
            long long grow = baserow + r;
            if (grow < N_NODES)
                Y[grow * D + nt * 16 + mrow] = bf(acc[nt][r]);
        }
}

// ---------------------------------------------------------------------------
// Gather: Z[n] = sum_e val_e * Y[src_e]. One 64-lane wave per dst row,
// lane = one bf16 pair (4B). 8-deep unrolled edge loop for MLP.
// ---------------------------------------------------------------------------
__global__ __launch_bounds__(256) void gather_kernel(
        const unsigned* __restrict__ Yu, const int* __restrict__ off,
        const unsigned* __restrict__ epack, float* __restrict__ Z) {
    const int n = blockIdx.x * 4 + (threadIdx.x >> 6);
    const int lane = threadIdx.x & 63;

    int e0 = off[n], e1 = off[n + 1];
    float ax = 0.f, ay = 0.f;
    const float q2f = 1.0f / 32767.0f;

    int e = e0;
    for (; e + 8 <= e1; e += 8) {
        unsigned p[8], y[8];
#pragma unroll
        for (int j = 0; j < 8; ++j) p[j] = epack[e + j];
#pragma unroll
        for (int j = 0; j < 8; ++j)
            y[j] = Yu[(long long)(p[j] & 0x1ffffu) * 64 + lane];
#pragma unroll
        for (int j = 0; j < 8; ++j) {
            float v = (float)(p[j] >> 17) * q2f;
            ax += v * __uint_as_float(y[j] << 16);
            ay += v * __uint_as_float(y[j] & 0xffff0000u);
        }
    }
    for (; e < e1; ++e) {
        unsigned p = epack[e];
        unsigned y = Yu[(long long)(p & 0x1ffffu) * 64 + lane];
        float v = (float)(p >> 17) * q2f;
        ax += v * __uint_as_float(y << 16);
        ay += v * __uint_as_float(y & 0xffff0000u);
    }

    ((float2*)Z)[(long long)n * 64 + lane] = make_float2(ax, ay);
}

// ---------------------------------------------------------------------------
extern "C" void kernel_launch(void* const* d_in, const int* in_sizes, int n_in,
                              void* d_out, int out_size, void* d_ws, size_t ws_size,
                              hipStream_t stream) {
    const float* x    = (const float*)d_in[0];   // [N_NODES, D]
    const float* W    = (const float*)d_in[1];   // [D, D]
    const int*   esrc = (const int*)  d_in[2];   // [N_EDGES]
    const int*   edst = (const int*)  d_in[3];   // [N_EDGES]
    const float* eval_= (const float*)d_in[4];   // [N_EDGES]
    float*       Z    = (float*)d_out;           // [N_NODES, D]

    // Workspace layout (bytes, all 16B-aligned starts)
    char* w = (char*)d_ws;
    int*      off        = (int*)     (w + 0);          // [N+1]            -> 400016
    int*      cnt        = (int*)     (w + 400016);     // [N]              -> 800016
    int*      partial    = (int*)     (w + 800016);     // [NCHUNK]         -> 800416
    int*      chunk_base = (int*)     (w + 800432);     // [NCHUNK]         -> 800832
    ushort_t* rank       = (ushort_t*)(w + 800848);     // [E] u16          -> 4000848
    unsigned* epack      = (unsigned*)(w + 4000848);    // [E] u32          -> 10400848
    ushort_t* Wt         = (ushort_t*)(w + 10400848);   // [128*128] bf16   -> 10433616
    ushort_t* Yu         = (ushort_t*)(w + 10433616);   // [N*128] bf16     -> 36033616

    zero_cnt_kernel<<<(N_NODES + 255) / 256, 256, 0, stream>>>(cnt);
    hist_rank_kernel<<<(N_EDGES + 255) / 256, 256, 0, stream>>>(edst, cnt, rank);
    scan1_kernel<<<NCHUNK, 256, 0, stream>>>(cnt, partial);
    scan2_kernel<<<1, 128, 0, stream>>>(partial, chunk_base);
    scan3_kernel<<<NCHUNK, 256, 0, stream>>>(cnt, chunk_base, off);
    scatter_pos_kernel<<<(N_EDGES + 255) / 256, 256, 0, stream>>>(esrc, edst, eval_, rank, off, epack);
    wt_conv_kernel<<<(D * D) / 256, 256, 0, stream>>>(W, Wt);
    gemm_xw_mfma<<<(N_NODES + 63) / 64, 256, 0, stream>>>(x, Wt, Yu);
    gather_kernel<<<N_NODES / 4, 256, 0, stream>>>((const unsigned*)Yu, off, epack, Z);
}